// Round 1
// baseline (3238.094 us; speedup 1.0000x reference)
//
#include <hip/hip_runtime.h>
#include <math.h>

#define BB 128
#define HH 512
#define SS 80
#define NT 27      // time steps (T-1)
#define VV 30000

// ---- workspace layout (in floats) ----
#define OFF_WE     0
#define OFF_CTX    512
#define OFF_H      (OFF_CTX + BB*HH)          // 66048
#define OFF_C      (OFF_H + BB*HH)            // 131584
#define OFF_GATES  (OFF_C + BB*HH)            // 197120
#define OFF_SLOTS  (OFF_GATES + BB*2048)      // 459264  (3456 u64 = 6912 floats)
#define OFF_GCTX   (OFF_SLOTS + 2*NT*BB)      // 466176
#define OFF_GIN    (OFF_GCTX + BB*2048)       // 728320
#define WS_FULL_FLOATS (OFF_GIN + NT*BB*2048) // 7,806,208 floats = ~31.2 MB

__device__ __forceinline__ unsigned long long pack_max(float v, int n) {
    unsigned u = __float_as_uint(v);
    unsigned key = (u & 0x80000000u) ? ~u : (u | 0x80000000u);
    return ((unsigned long long)key << 32) | (unsigned)(~(unsigned)n);
}

// ---------------- init: h = elhs, c = 0, slots = 0 ----------------
__global__ void k_init(const float* __restrict__ elhs, float* __restrict__ h,
                       float* __restrict__ c, unsigned long long* __restrict__ slots) {
    int i = blockIdx.x * blockDim.x + threadIdx.x;
    if (i < BB * HH) { h[i] = elhs[i]; c[i] = 0.f; }
    if (i < NT * BB) slots[i] = 0ull;
}

// ---------------- we = W1e^T W2^T W3^T W4^T w_att ----------------
__global__ __launch_bounds__(256) void k_we(const float* __restrict__ W1, const float* __restrict__ W2,
                                            const float* __restrict__ W3, const float* __restrict__ W4,
                                            const float* __restrict__ watt, float* __restrict__ we_out) {
    __shared__ float v[HH], v2[HH];
    int tid = threadIdx.x;
    for (int k = tid; k < HH; k += 256) v[k] = watt[k];
    __syncthreads();
    const float* Ws[3] = {W4, W3, W2};
    for (int l = 0; l < 3; ++l) {
        const float* W = Ws[l];
        for (int k = tid; k < HH; k += 256) {
            float s = 0.f;
            for (int j = 0; j < HH; ++j) s += v[j] * W[j * HH + k];
            v2[k] = s;
        }
        __syncthreads();
        for (int k = tid; k < HH; k += 256) v[k] = v2[k];
        __syncthreads();
    }
    for (int k = tid; k < HH; k += 256) {
        float s = 0.f;
        for (int j = 0; j < HH; ++j) s += v[j] * W1[j * (2 * HH) + k];  // first H columns of W1
        we_out[k] = s;
    }
}

// ---------------- attention: scores -> softmax -> ctx (step-invariant!) ----------------
__global__ __launch_bounds__(256) void k_attn(const float* __restrict__ eo, const float* __restrict__ we,
                                              float* __restrict__ ctx) {
    __shared__ float wsm[HH];
    __shared__ float sc[SS];
    int b = blockIdx.x, tid = threadIdx.x;
    for (int k = tid; k < HH; k += 256) wsm[k] = we[k];
    __syncthreads();
    int wid = tid >> 6, lane = tid & 63;
    const float* eob = eo + (size_t)b * SS * HH;
    for (int s = wid; s < SS; s += 4) {
        float p = 0.f;
        for (int k = lane; k < HH; k += 64) p += eob[s * HH + k] * wsm[k];
        for (int off = 32; off > 0; off >>= 1) p += __shfl_down(p, off, 64);
        if (lane == 0) sc[s] = p;
    }
    __syncthreads();
    if (wid == 0) {
        float a = (lane < SS) ? sc[lane] : -INFINITY;
        float bv = (lane + 64 < SS) ? sc[lane + 64] : -INFINITY;
        float m = fmaxf(a, bv);
        for (int off = 32; off > 0; off >>= 1) m = fmaxf(m, __shfl_down(m, off, 64));
        m = __shfl(m, 0, 64);
        float e0 = (lane < SS) ? expf(a - m) : 0.f;
        float e1 = (lane + 64 < SS) ? expf(bv - m) : 0.f;
        float ssum = e0 + e1;
        for (int off = 32; off > 0; off >>= 1) ssum += __shfl_down(ssum, off, 64);
        ssum = __shfl(ssum, 0, 64);
        float inv = 1.f / ssum;
        if (lane < SS) sc[lane] = e0 * inv;
        if (lane + 64 < SS) sc[lane + 64] = e1 * inv;
    }
    __syncthreads();
    for (int hh = tid; hh < HH; hh += 256) {
        float acc = 0.f;
        for (int s = 0; s < SS; ++s) acc += sc[s] * eob[s * HH + hh];
        ctx[b * HH + hh] = acc;
    }
}

// ---------------- G_in = X @ W_ih[:, :512]^T   (M=3456, N=2048, K=512) ----------------
__global__ __launch_bounds__(256) void k_gin(const float* __restrict__ emb, const int* __restrict__ targets,
                                             const float* __restrict__ Wih, float* __restrict__ gin) {
    const int n0 = blockIdx.x * 64, m0 = blockIdx.y * 64;
    __shared__ __align__(16) float As[32][68];
    __shared__ __align__(16) float Bs[32][68];
    int tid = threadIdx.x;
    int tx = tid & 15, ty = tid >> 4;
    float acc[4][4] = {};
    for (int kt = 0; kt < 512; kt += 32) {
        #pragma unroll
        for (int i = 0; i < 2; ++i) {
            int idx = tid + i * 256;
            int mm = idx >> 3, k4 = (idx & 7) * 4;
            int m = m0 + mm;
            int t = m >> 7, b = m & 127;
            int row = targets[b * 28 + t];
            float4 v = *(const float4*)(emb + (size_t)row * 512 + kt + k4);
            As[k4 + 0][mm] = v.x; As[k4 + 1][mm] = v.y; As[k4 + 2][mm] = v.z; As[k4 + 3][mm] = v.w;
        }
        #pragma unroll
        for (int i = 0; i < 2; ++i) {
            int idx = tid + i * 256;
            int nn = idx >> 3, k4 = (idx & 7) * 4;
            float4 v = *(const float4*)(Wih + (size_t)(n0 + nn) * 1024 + kt + k4);
            Bs[k4 + 0][nn] = v.x; Bs[k4 + 1][nn] = v.y; Bs[k4 + 2][nn] = v.z; Bs[k4 + 3][nn] = v.w;
        }
        __syncthreads();
        #pragma unroll
        for (int k = 0; k < 32; ++k) {
            float4 a = *(const float4*)&As[k][ty * 4];
            float4 b4 = *(const float4*)&Bs[k][tx * 4];
            float av[4] = {a.x, a.y, a.z, a.w}, bv[4] = {b4.x, b4.y, b4.z, b4.w};
            #pragma unroll
            for (int i = 0; i < 4; ++i)
                #pragma unroll
                for (int j = 0; j < 4; ++j) acc[i][j] += av[i] * bv[j];
        }
        __syncthreads();
    }
    #pragma unroll
    for (int i = 0; i < 4; ++i) {
        int m = m0 + ty * 4 + i;
        float4 o = {acc[i][0], acc[i][1], acc[i][2], acc[i][3]};
        *(float4*)(gin + (size_t)m * 2048 + n0 + tx * 4) = o;
    }
}

// ---------------- gctx = ctx @ W_ih[:, 512:]^T + b_ih + b_hh  (M=128,N=2048,K=512) ----------------
__global__ __launch_bounds__(256) void k_gctx(const float* __restrict__ ctx, const float* __restrict__ Wih,
                                              const float* __restrict__ bih, const float* __restrict__ bhh,
                                              float* __restrict__ gctx) {
    const int n0 = blockIdx.x * 64, m0 = blockIdx.y * 32;
    __shared__ __align__(16) float As[32][36];
    __shared__ __align__(16) float Bs[32][68];
    int tid = threadIdx.x;
    int tx = tid & 15, ty = tid >> 4;
    float acc[2][4] = {};
    for (int kt = 0; kt < 512; kt += 32) {
        {
            int mm = tid >> 3, k4 = (tid & 7) * 4;
            float4 v = *(const float4*)(ctx + (size_t)(m0 + mm) * 512 + kt + k4);
            As[k4 + 0][mm] = v.x; As[k4 + 1][mm] = v.y; As[k4 + 2][mm] = v.z; As[k4 + 3][mm] = v.w;
        }
        #pragma unroll
        for (int i = 0; i < 2; ++i) {
            int idx = tid + i * 256;
            int nn = idx >> 3, k4 = (idx & 7) * 4;
            float4 v = *(const float4*)(Wih + (size_t)(n0 + nn) * 1024 + 512 + kt + k4);
            Bs[k4 + 0][nn] = v.x; Bs[k4 + 1][nn] = v.y; Bs[k4 + 2][nn] = v.z; Bs[k4 + 3][nn] = v.w;
        }
        __syncthreads();
        #pragma unroll
        for (int k = 0; k < 32; ++k) {
            float a0 = As[k][ty * 2], a1 = As[k][ty * 2 + 1];
            float4 b4 = *(const float4*)&Bs[k][tx * 4];
            float bv[4] = {b4.x, b4.y, b4.z, b4.w};
            #pragma unroll
            for (int j = 0; j < 4; ++j) { acc[0][j] += a0 * bv[j]; acc[1][j] += a1 * bv[j]; }
        }
        __syncthreads();
    }
    #pragma unroll
    for (int i = 0; i < 2; ++i) {
        int b = m0 + ty * 2 + i;
        int n = n0 + tx * 4;
        float4 o = {acc[i][0] + bih[n] + bhh[n], acc[i][1] + bih[n + 1] + bhh[n + 1],
                    acc[i][2] + bih[n + 2] + bhh[n + 2], acc[i][3] + bih[n + 3] + bhh[n + 3]};
        *(float4*)(gctx + (size_t)b * 2048 + n) = o;
    }
}

// ---------------- gates GEMM. FULL=true: K=1536 (emb|ctx|h), bias init. FULL=false: K=512 (h only), init from gin+gctx ----------------
template <bool FULL>
__global__ __launch_bounds__(256) void k_gates(const float* __restrict__ emb, const int* __restrict__ targets,
                                               const float* __restrict__ ctx, const float* __restrict__ h,
                                               const float* __restrict__ Wih, const float* __restrict__ Whh,
                                               const float* __restrict__ bih, const float* __restrict__ bhh,
                                               const float* __restrict__ gin, const float* __restrict__ gctx,
                                               float* __restrict__ gates, int t) {
    const int n0 = blockIdx.x * 64, m0 = blockIdx.y * 32;
    __shared__ __align__(16) float As[32][36];
    __shared__ __align__(16) float Bs[32][68];
    int tid = threadIdx.x;
    int tx = tid & 15, ty = tid >> 4;
    float acc[2][4] = {};
    const int KTOT = FULL ? 1536 : 512;
    for (int kt = 0; kt < KTOT; kt += 32) {
        {
            int mm = tid >> 3, k4 = (tid & 7) * 4;
            int b = m0 + mm, k = kt + k4;
            const float* src;
            if (FULL) {
                if (k < 512) { int row = targets[b * 28 + t]; src = emb + (size_t)row * 512 + k; }
                else if (k < 1024) src = ctx + (size_t)b * 512 + (k - 512);
                else src = h + (size_t)b * 512 + (k - 1024);
            } else {
                src = h + (size_t)b * 512 + k;
            }
            float4 v = *(const float4*)src;
            As[k4 + 0][mm] = v.x; As[k4 + 1][mm] = v.y; As[k4 + 2][mm] = v.z; As[k4 + 3][mm] = v.w;
        }
        #pragma unroll
        for (int i = 0; i < 2; ++i) {
            int idx = tid + i * 256;
            int nn = idx >> 3, k4 = (idx & 7) * 4;
            int n = n0 + nn, k = kt + k4;
            const float* src;
            if (FULL) {
                if (k < 1024) src = Wih + (size_t)n * 1024 + k;
                else src = Whh + (size_t)n * 512 + (k - 1024);
            } else {
                src = Whh + (size_t)n * 512 + k;
            }
            float4 v = *(const float4*)src;
            Bs[k4 + 0][nn] = v.x; Bs[k4 + 1][nn] = v.y; Bs[k4 + 2][nn] = v.z; Bs[k4 + 3][nn] = v.w;
        }
        __syncthreads();
        #pragma unroll
        for (int k = 0; k < 32; ++k) {
            float a0 = As[k][ty * 2], a1 = As[k][ty * 2 + 1];
            float4 b4 = *(const float4*)&Bs[k][tx * 4];
            float bv[4] = {b4.x, b4.y, b4.z, b4.w};
            #pragma unroll
            for (int j = 0; j < 4; ++j) { acc[0][j] += a0 * bv[j]; acc[1][j] += a1 * bv[j]; }
        }
        __syncthreads();
    }
    #pragma unroll
    for (int i = 0; i < 2; ++i) {
        int b = m0 + ty * 2 + i;
        int n = n0 + tx * 4;
        float base[4];
        if (FULL) {
            #pragma unroll
            for (int j = 0; j < 4; ++j) base[j] = bih[n + j] + bhh[n + j];
        } else {
            const float* g1 = gin + ((size_t)t * BB + b) * 2048 + n;
            const float* g2 = gctx + (size_t)b * 2048 + n;
            #pragma unroll
            for (int j = 0; j < 4; ++j) base[j] = g1[j] + g2[j];
        }
        float4 o = {acc[i][0] + base[0], acc[i][1] + base[1], acc[i][2] + base[2], acc[i][3] + base[3]};
        *(float4*)(gates + (size_t)b * 2048 + n) = o;
    }
}

// ---------------- LSTM pointwise ----------------
__global__ void k_lstm(const float* __restrict__ gates, float* __restrict__ h, float* __restrict__ c) {
    int idx = blockIdx.x * blockDim.x + threadIdx.x;  // 128*512
    int b = idx >> 9, j = idx & 511;
    const float* g = gates + (size_t)b * 2048;
    float iv = g[j], fv = g[512 + j], gv = g[1024 + j], ov = g[1536 + j];
    float si = 1.f / (1.f + expf(-iv));
    float sf = 1.f / (1.f + expf(-fv));
    float so = 1.f / (1.f + expf(-ov));
    float c2 = sf * c[idx] + si * tanhf(gv);
    c[idx] = c2;
    h[idx] = so * tanhf(c2);
}

// ---------------- vocab projection + logits write + fused argmax ----------------
__global__ __launch_bounds__(256) void k_vproj(const float* __restrict__ h, const float* __restrict__ Wout,
                                               const float* __restrict__ bout, float* __restrict__ out,
                                               unsigned long long* __restrict__ slots, int t) {
    const int n0 = blockIdx.x * 64, m0 = blockIdx.y * 64;
    __shared__ __align__(16) float As[32][68];
    __shared__ __align__(16) float Bs[32][68];
    __shared__ unsigned long long red[64][17];
    int tid = threadIdx.x;
    int tx = tid & 15, ty = tid >> 4;
    float acc[4][4] = {};
    for (int kt = 0; kt < 512; kt += 32) {
        #pragma unroll
        for (int i = 0; i < 2; ++i) {
            int idx = tid + i * 256;
            int mm = idx >> 3, k4 = (idx & 7) * 4;
            float4 v = *(const float4*)(h + (size_t)(m0 + mm) * 512 + kt + k4);
            As[k4 + 0][mm] = v.x; As[k4 + 1][mm] = v.y; As[k4 + 2][mm] = v.z; As[k4 + 3][mm] = v.w;
        }
        #pragma unroll
        for (int i = 0; i < 2; ++i) {
            int idx = tid + i * 256;
            int nn = idx >> 3, k4 = (idx & 7) * 4;
            int n = n0 + nn; if (n >= VV) n = VV - 1;
            float4 v = *(const float4*)(Wout + (size_t)n * 512 + kt + k4);
            Bs[k4 + 0][nn] = v.x; Bs[k4 + 1][nn] = v.y; Bs[k4 + 2][nn] = v.z; Bs[k4 + 3][nn] = v.w;
        }
        __syncthreads();
        #pragma unroll
        for (int k = 0; k < 32; ++k) {
            float4 a = *(const float4*)&As[k][ty * 4];
            float4 b4 = *(const float4*)&Bs[k][tx * 4];
            float av[4] = {a.x, a.y, a.z, a.w}, bv[4] = {b4.x, b4.y, b4.z, b4.w};
            #pragma unroll
            for (int i = 0; i < 4; ++i)
                #pragma unroll
                for (int j = 0; j < 4; ++j) acc[i][j] += av[i] * bv[j];
        }
        __syncthreads();
    }
    #pragma unroll
    for (int i = 0; i < 4; ++i) {
        int m = m0 + ty * 4 + i;  // batch row b
        int n = n0 + tx * 4;
        float vals[4];
        #pragma unroll
        for (int j = 0; j < 4; ++j) vals[j] = acc[i][j] + ((n + j < VV) ? bout[n + j] : 0.f);
        size_t ob = ((size_t)m * NT + t) * VV;
        if (n + 3 < VV) {
            float4 o = {vals[0], vals[1], vals[2], vals[3]};
            *(float4*)(out + ob + n) = o;
        } else {
            for (int j = 0; j < 4; ++j) if (n + j < VV) out[ob + n + j] = vals[j];
        }
        unsigned long long p = 0ull;
        #pragma unroll
        for (int j = 0; j < 4; ++j)
            if (n + j < VV) {
                unsigned long long pk = pack_max(vals[j], n + j);
                if (pk > p) p = pk;
            }
        red[ty * 4 + i][tx] = p;
    }
    __syncthreads();
    if (tid < 64) {
        unsigned long long best = red[tid][0];
        #pragma unroll
        for (int j = 1; j < 16; ++j) { unsigned long long q = red[tid][j]; if (q > best) best = q; }
        atomicMax(&slots[t * BB + (m0 + tid)], best);
    }
}

// ---------------- decode predictions ----------------
__global__ void k_final(const unsigned long long* __restrict__ slots, float* __restrict__ out) {
    int i = blockIdx.x * blockDim.x + threadIdx.x;
    if (i >= NT * BB) return;
    int t = i / BB, b = i % BB;
    unsigned idx = ~(unsigned)(slots[i] & 0xffffffffull);
    out[(size_t)BB * NT * VV + (size_t)b * NT + t] = (float)idx;
}

extern "C" void kernel_launch(void* const* d_in, const int* in_sizes, int n_in,
                              void* d_out, int out_size, void* d_ws, size_t ws_size,
                              hipStream_t stream) {
    const float* elhs    = (const float*)d_in[0];
    const float* eo      = (const float*)d_in[1];
    const int*   targets = (const int*)d_in[2];
    const float* emb     = (const float*)d_in[3];
    const float* W1      = (const float*)d_in[4];
    const float* W2      = (const float*)d_in[6];
    const float* W3      = (const float*)d_in[8];
    const float* W4      = (const float*)d_in[10];
    const float* watt    = (const float*)d_in[12];
    const float* Wih     = (const float*)d_in[13];
    const float* Whh     = (const float*)d_in[14];
    const float* bih     = (const float*)d_in[15];
    const float* bhh     = (const float*)d_in[16];
    const float* Wout    = (const float*)d_in[17];
    const float* bout    = (const float*)d_in[18];

    float* out = (float*)d_out;
    float* ws  = (float*)d_ws;
    float* we    = ws + OFF_WE;
    float* ctx   = ws + OFF_CTX;
    float* h     = ws + OFF_H;
    float* c     = ws + OFF_C;
    float* gates = ws + OFF_GATES;
    unsigned long long* slots = (unsigned long long*)(ws + OFF_SLOTS);
    float* gctx  = ws + OFF_GCTX;
    float* gin   = ws + OFF_GIN;

    const bool use_gin = ws_size >= (size_t)WS_FULL_FLOATS * sizeof(float);

    k_init<<<256, 256, 0, stream>>>(elhs, h, c, slots);
    k_we<<<1, 256, 0, stream>>>(W1, W2, W3, W4, watt, we);
    k_attn<<<BB, 256, 0, stream>>>(eo, we, ctx);
    if (use_gin) {
        k_gin<<<dim3(32, 54), 256, 0, stream>>>(emb, targets, Wih, gin);
        k_gctx<<<dim3(32, 4), 256, 0, stream>>>(ctx, Wih, bih, bhh, gctx);
    }
    for (int t = 0; t < NT; ++t) {
        if (use_gin)
            k_gates<false><<<dim3(32, 4), 256, 0, stream>>>(emb, targets, ctx, h, Wih, Whh, bih, bhh, gin, gctx, gates, t);
        else
            k_gates<true><<<dim3(32, 4), 256, 0, stream>>>(emb, targets, ctx, h, Wih, Whh, bih, bhh, gin, gctx, gates, t);
        k_lstm<<<128, 512, 0, stream>>>(gates, h, c);
        k_vproj<<<dim3(469, 2), 256, 0, stream>>>(h, Wout, bout, out, slots, t);
    }
    k_final<<<14, 256, 0, stream>>>(slots, out);
}